// Round 10
// baseline (118.407 us; speedup 1.0000x reference)
//
#include <hip/hip_runtime.h>
#include <math.h>

// Problem constants (fixed by the reference's setup_inputs)
#define BB 32
#define LL 40
#define HH 448
#define SS 8000
#define NC 25
#define H4 (HH / 4)     // 112 float4 per row
#define NBLK (SS / 4)   // 2000 score blocks, 4 waves (segments) each

// Native Clang vector (works with __builtin_nontemporal_load, unlike HIP float4)
typedef float f4 __attribute__((ext_vector_type(4)));

// ---------------- Kernel 1: x_pool[b,k] = sum_{l,h} x[b,l,h] * W[k,h] ----------------
// grid: (BB, 14). Phase-1 pools x[b] over L with float4 loads. Phase-2: 32 k
// per block, 8 lanes cooperate per k.
__global__ __launch_bounds__(256) void pool_kernel(const float* __restrict__ x,
                                                   const float* __restrict__ W,
                                                   float* __restrict__ xpool) {
    __shared__ f4 xsum4[H4];    // pooled row, as 112 float4
    __shared__ f4 part1[H4];    // partial for l-group 1
    const int b = blockIdx.x;
    const int kc = blockIdx.y;
    const int tid = threadIdx.x;
    const f4* xb4 = (const f4*)(x + (size_t)b * LL * HH);

    // Phase 1 (vectorized): threads 0..223; h4 = t%112, l-group = t/112.
    if (tid < 2 * H4) {
        const int h4 = tid % H4;
        const int lg = tid / H4;
        f4 acc = {0.f, 0.f, 0.f, 0.f};
        #pragma unroll 5
        for (int i = 0; i < LL / 2; ++i) {
            acc += xb4[(size_t)(lg + 2 * i) * H4 + h4];
        }
        if (lg == 0) xsum4[h4] = acc;
        else         part1[h4] = acc;
    }
    __syncthreads();
    if (tid < H4) xsum4[tid] += part1[tid];
    __syncthreads();

    // Phase 2: 32 k-values per block; 8 lanes cooperate on each k.
    const float* xsum = (const float*)xsum4;
    const int kk  = tid >> 3;          // 0..31  (k within chunk)
    const int sub = tid & 7;           // 0..7   (lane within octet)
    const int k   = kc * 32 + kk;
    const f4* wr = (const f4*)(W + (size_t)k * HH);
    float acc = 0.f;
    #pragma unroll 14
    for (int j = sub; j < H4; j += 8) {   // 14 independent iterations
        f4 w4 = wr[j];
        acc += xsum[j * 4 + 0] * w4.x;
        acc += xsum[j * 4 + 1] * w4.y;
        acc += xsum[j * 4 + 2] * w4.z;
        acc += xsum[j * 4 + 3] * w4.w;
    }
    // reduce across the octet (sub = 0..7)
    acc += __shfl_xor(acc, 1, 64);
    acc += __shfl_xor(acc, 2, 64);
    acc += __shfl_xor(acc, 4, 64);
    if (sub == 0) xpool[b * HH + k] = acc;
}

// ---------------- Kernel 2: one wave per segment; scores + online softmax ----------------
// nt loads restored (R9 A/B: removing them cost +5 us — evict-first protects
// L2/L3 from the 358 MB stream). R10 delta: per-block atomicAdd epilogue into
// d_out (device-scope, NO fences — R7's poison was __threadfence, not atomics).
__global__ __launch_bounds__(256) void score_kernel(
        const float* __restrict__ cand,
        const float* __restrict__ xpool,
        const int* __restrict__ batch_idx,
        const int* __restrict__ label_in_seg,
        float* __restrict__ out) {
    __shared__ float s_loss[4];
    __shared__ float s_acc[4];
    const int wave = threadIdx.x >> 6;
    const int lane = threadIdx.x & 63;
    const int seg = blockIdx.x * 4 + wave;   // SS = 4 * gridDim.x exactly

    const int label = label_in_seg[seg];
    const long t0 = (long)seg * NC;

    float m = -INFINITY;
    float ssum = 0.f;
    float label_score = 0.f;

    for (int c = 0; c < NC; ++c) {
        const long t = t0 + c;
        const int bi = batch_idx[t];        // wave-uniform load; keeps the
                                            // candidate loop unrolled/pipelined
        const f4* cr = (const f4*)(cand + t * (long)HH);
        const f4* xr = (const f4*)(xpool + bi * HH);

        // 112 float4 covered by: lane (all 64) + 64+lane (lanes < 48)
        f4 a = __builtin_nontemporal_load(cr + lane);   // streamed, evict-first
        f4 b = xr[lane];                                // L2-hot (57 KB total)
        float p = a.x * b.x + a.y * b.y + a.z * b.z + a.w * b.w;
        if (lane < 48) {
            f4 a2 = __builtin_nontemporal_load(cr + 64 + lane);
            f4 b2 = xr[64 + lane];
            p += a2.x * b2.x + a2.y * b2.y + a2.z * b2.z + a2.w * b2.w;
        }

        // 64-lane butterfly: every lane ends with the full dot
        #pragma unroll
        for (int off = 32; off > 0; off >>= 1) p += __shfl_xor(p, off, 64);

        const float score = p;
        if (c == label) label_score = score;
        const float nm = fmaxf(m, score);
        ssum = ssum * __expf(m - nm) + __expf(score - nm);
        m = nm;
    }

    if (lane == 0) {
        const float lse = m + __logf(ssum);
        s_loss[wave] = lse - label_score;
        s_acc[wave] = (label_score >= m) ? 1.f : 0.f;
    }
    __syncthreads();
    if (threadIdx.x == 0) {
        // One pair of device-scope atomics per block; arrivals staggered over
        // the kernel's span -> negligible contention on 2 addresses.
        atomicAdd(&out[0], ((s_loss[0] + s_loss[1]) + (s_loss[2] + s_loss[3]))
                               * (1.f / (float)BB));
        atomicAdd(&out[1], ((s_acc[0] + s_acc[1]) + (s_acc[2] + s_acc[3]))
                               * (1.f / (float)SS));
    }
}

extern "C" void kernel_launch(void* const* d_in, const int* in_sizes, int n_in,
                              void* d_out, int out_size, void* d_ws, size_t ws_size,
                              hipStream_t stream) {
    const float* x_mol   = (const float*)d_in[0];   // [32,40,448] f32
    const float* cand    = (const float*)d_in[1];   // [200000,448] f32
    const float* W       = (const float*)d_in[2];   // [448,448] f32
    const int*   bidx    = (const int*)d_in[3];     // [200000] i32
    const int*   label   = (const int*)d_in[4];     // [8000] i32
    float* out = (float*)d_out;                     // [loss, acc]

    // Workspace: xpool[32*448] f32
    float* xpool = (float*)d_ws;                    // 14336 floats

    hipMemsetAsync(out, 0, 2 * sizeof(float), stream);   // atomics accumulate
    dim3 pgrid(BB, 14);
    pool_kernel<<<pgrid, 256, 0, stream>>>(x_mol, W, xpool);
    score_kernel<<<NBLK, 256, 0, stream>>>(cand, xpool, bidx, label, out);
}

// Round 11
// 69.684 us; speedup vs baseline: 1.6992x; 1.6992x over previous
//
#include <hip/hip_runtime.h>
#include <math.h>

// Problem constants (fixed by the reference's setup_inputs)
#define BB 32
#define LL 40
#define HH 448
#define SS 8000
#define NC 25
#define H4 (HH / 4)     // 112 float4 per row
#define NBLK (SS / 4)   // 2000 score blocks, 4 waves (segments) each
#define PIN_BLK 950     // blocks < PIN_BLK use plain (L3-retained) cand loads:
                        // 950 blk * 4 seg * 25 cand * 1792 B = 170 MB < 256 MB L3

// Native Clang vector (works with __builtin_nontemporal_load, unlike HIP float4)
typedef float f4 __attribute__((ext_vector_type(4)));

// ---------------- Kernel 1: x_pool[b,k] = sum_{l,h} x[b,l,h] * W[k,h] ----------------
__global__ __launch_bounds__(256) void pool_kernel(const float* __restrict__ x,
                                                   const float* __restrict__ W,
                                                   float* __restrict__ xpool) {
    __shared__ f4 xsum4[H4];    // pooled row, as 112 float4
    __shared__ f4 part1[H4];    // partial for l-group 1
    const int b = blockIdx.x;
    const int kc = blockIdx.y;
    const int tid = threadIdx.x;
    const f4* xb4 = (const f4*)(x + (size_t)b * LL * HH);

    // Phase 1 (vectorized): threads 0..223; h4 = t%112, l-group = t/112.
    if (tid < 2 * H4) {
        const int h4 = tid % H4;
        const int lg = tid / H4;
        f4 acc = {0.f, 0.f, 0.f, 0.f};
        #pragma unroll 5
        for (int i = 0; i < LL / 2; ++i) {
            acc += xb4[(size_t)(lg + 2 * i) * H4 + h4];
        }
        if (lg == 0) xsum4[h4] = acc;
        else         part1[h4] = acc;
    }
    __syncthreads();
    if (tid < H4) xsum4[tid] += part1[tid];
    __syncthreads();

    // Phase 2: 32 k-values per block; 8 lanes cooperate on each k.
    const float* xsum = (const float*)xsum4;
    const int kk  = tid >> 3;          // 0..31  (k within chunk)
    const int sub = tid & 7;           // 0..7   (lane within octet)
    const int k   = kc * 32 + kk;
    const f4* wr = (const f4*)(W + (size_t)k * HH);
    float acc = 0.f;
    #pragma unroll 14
    for (int j = sub; j < H4; j += 8) {   // 14 independent iterations
        f4 w4 = wr[j];
        acc += xsum[j * 4 + 0] * w4.x;
        acc += xsum[j * 4 + 1] * w4.y;
        acc += xsum[j * 4 + 2] * w4.z;
        acc += xsum[j * 4 + 3] * w4.w;
    }
    // reduce across the octet (sub = 0..7)
    acc += __shfl_xor(acc, 1, 64);
    acc += __shfl_xor(acc, 2, 64);
    acc += __shfl_xor(acc, 4, 64);
    if (sub == 0) xpool[b * HH + k] = acc;
}

// ---------------- Kernel 2 body: one wave per segment; scores + online softmax ----------------
// NT=true: evict-first stream (R8 behavior). NT=false: plain loads so the
// Infinity Cache retains this slice of cand across graph replays.
template <bool NT>
__device__ __forceinline__ void score_body(
        const float* __restrict__ cand,
        const float* __restrict__ xpool,
        const int* __restrict__ batch_idx,
        const int* __restrict__ label_in_seg,
        float* __restrict__ blk_loss,
        float* __restrict__ blk_acc,
        float* s_loss, float* s_acc) {
    const int wave = threadIdx.x >> 6;
    const int lane = threadIdx.x & 63;
    const int seg = blockIdx.x * 4 + wave;   // SS = 4 * gridDim.x exactly

    const int label = label_in_seg[seg];
    const long t0 = (long)seg * NC;

    float m = -INFINITY;
    float ssum = 0.f;
    float label_score = 0.f;

    for (int c = 0; c < NC; ++c) {
        const long t = t0 + c;
        const int bi = batch_idx[t];        // wave-uniform load; keeps the
                                            // candidate loop unrolled/pipelined
        const f4* cr = (const f4*)(cand + t * (long)HH);
        const f4* xr = (const f4*)(xpool + bi * HH);

        // 112 float4 covered by: lane (all 64) + 64+lane (lanes < 48)
        f4 a = NT ? __builtin_nontemporal_load(cr + lane) : cr[lane];
        f4 b = xr[lane];                    // L2-hot (57 KB total)
        float p = a.x * b.x + a.y * b.y + a.z * b.z + a.w * b.w;
        if (lane < 48) {
            f4 a2 = NT ? __builtin_nontemporal_load(cr + 64 + lane) : cr[64 + lane];
            f4 b2 = xr[64 + lane];
            p += a2.x * b2.x + a2.y * b2.y + a2.z * b2.z + a2.w * b2.w;
        }

        // 64-lane butterfly: every lane ends with the full dot
        #pragma unroll
        for (int off = 32; off > 0; off >>= 1) p += __shfl_xor(p, off, 64);

        const float score = p;
        if (c == label) label_score = score;
        const float nm = fmaxf(m, score);
        ssum = ssum * __expf(m - nm) + __expf(score - nm);
        m = nm;
    }

    if (lane == 0) {
        const float lse = m + __logf(ssum);
        s_loss[wave] = lse - label_score;
        s_acc[wave] = (label_score >= m) ? 1.f : 0.f;
    }
    __syncthreads();
    if (threadIdx.x == 0) {
        blk_loss[blockIdx.x] = (s_loss[0] + s_loss[1]) + (s_loss[2] + s_loss[3]);
        blk_acc[blockIdx.x]  = (s_acc[0] + s_acc[1]) + (s_acc[2] + s_acc[3]);
    }
}

__global__ __launch_bounds__(256) void score_kernel(
        const float* __restrict__ cand,
        const float* __restrict__ xpool,
        const int* __restrict__ batch_idx,
        const int* __restrict__ label_in_seg,
        float* __restrict__ blk_loss,
        float* __restrict__ blk_acc) {
    __shared__ float s_loss[4];
    __shared__ float s_acc[4];
    if (blockIdx.x < PIN_BLK)
        score_body<false>(cand, xpool, batch_idx, label_in_seg,
                          blk_loss, blk_acc, s_loss, s_acc);
    else
        score_body<true>(cand, xpool, batch_idx, label_in_seg,
                         blk_loss, blk_acc, s_loss, s_acc);
}

// ---------------- Kernel 3: deterministic fixed-order final reduction ----------------
__global__ __launch_bounds__(256) void reduce_kernel(const float* __restrict__ blk_loss,
                                                     const float* __restrict__ blk_acc,
                                                     float* __restrict__ out) {
    __shared__ float sl[256];
    __shared__ float sa[256];
    const int tid = threadIdx.x;
    float l = 0.f, a = 0.f;
    for (int s = tid; s < NBLK; s += 256) {
        l += blk_loss[s];
        a += blk_acc[s];
    }
    sl[tid] = l;
    sa[tid] = a;
    __syncthreads();
    for (int off = 128; off > 0; off >>= 1) {
        if (tid < off) {
            sl[tid] += sl[tid + off];
            sa[tid] += sa[tid + off];
        }
        __syncthreads();
    }
    if (tid == 0) {
        out[0] = sl[0] / (float)BB;   // loss = sum(lse - label_score) / nbatch
        out[1] = sa[0] / (float)SS;   // acc  = mean(label >= seg_max)
    }
}

extern "C" void kernel_launch(void* const* d_in, const int* in_sizes, int n_in,
                              void* d_out, int out_size, void* d_ws, size_t ws_size,
                              hipStream_t stream) {
    const float* x_mol   = (const float*)d_in[0];   // [32,40,448] f32
    const float* cand    = (const float*)d_in[1];   // [200000,448] f32
    const float* W       = (const float*)d_in[2];   // [448,448] f32
    const int*   bidx    = (const int*)d_in[3];     // [200000] i32
    const int*   label   = (const int*)d_in[4];     // [8000] i32
    float* out = (float*)d_out;                     // [loss, acc]

    // Workspace layout (floats): xpool[32*448] | blk_loss[2000] | blk_acc[2000]
    float* ws       = (float*)d_ws;
    float* xpool    = ws;                 // 14336 floats
    float* blk_loss = ws + BB * HH;       // 2000 floats
    float* blk_acc  = blk_loss + NBLK;    // 2000 floats

    dim3 pgrid(BB, 14);
    pool_kernel<<<pgrid, 256, 0, stream>>>(x_mol, W, xpool);
    score_kernel<<<NBLK, 256, 0, stream>>>(cand, xpool, bidx, label,
                                           blk_loss, blk_acc);
    reduce_kernel<<<1, 256, 0, stream>>>(blk_loss, blk_acc, out);
}

// Round 12
// 67.722 us; speedup vs baseline: 1.7484x; 1.0290x over previous
//
#include <hip/hip_runtime.h>
#include <math.h>

// Problem constants (fixed by the reference's setup_inputs)
#define BB 32
#define LL 40
#define HH 448
#define SS 8000
#define NC 25
#define H4 (HH / 4)     // 112 float4 per row
#define NBLK (SS / 4)   // 2000 score blocks, 4 waves (segments) each
#define PIN_BLK 1250    // blocks < PIN_BLK use plain (L3-retained) cand loads:
                        // 1250 blk * 4 seg * 25 cand * 1792 B = 224 MB < 256 MB L3
                        // (R11 A/B: 950 blk / 170 MB pinned = -6.5 us vs all-nt)

// Native Clang vector (works with __builtin_nontemporal_load, unlike HIP float4)
typedef float f4 __attribute__((ext_vector_type(4)));

// ---------------- Kernel 1: x_pool[b,k] = sum_{l,h} x[b,l,h] * W[k,h] ----------------
__global__ __launch_bounds__(256) void pool_kernel(const float* __restrict__ x,
                                                   const float* __restrict__ W,
                                                   float* __restrict__ xpool) {
    __shared__ f4 xsum4[H4];    // pooled row, as 112 float4
    __shared__ f4 part1[H4];    // partial for l-group 1
    const int b = blockIdx.x;
    const int kc = blockIdx.y;
    const int tid = threadIdx.x;
    const f4* xb4 = (const f4*)(x + (size_t)b * LL * HH);

    // Phase 1 (vectorized): threads 0..223; h4 = t%112, l-group = t/112.
    if (tid < 2 * H4) {
        const int h4 = tid % H4;
        const int lg = tid / H4;
        f4 acc = {0.f, 0.f, 0.f, 0.f};
        #pragma unroll 5
        for (int i = 0; i < LL / 2; ++i) {
            acc += xb4[(size_t)(lg + 2 * i) * H4 + h4];
        }
        if (lg == 0) xsum4[h4] = acc;
        else         part1[h4] = acc;
    }
    __syncthreads();
    if (tid < H4) xsum4[tid] += part1[tid];
    __syncthreads();

    // Phase 2: 32 k-values per block; 8 lanes cooperate on each k.
    const float* xsum = (const float*)xsum4;
    const int kk  = tid >> 3;          // 0..31  (k within chunk)
    const int sub = tid & 7;           // 0..7   (lane within octet)
    const int k   = kc * 32 + kk;
    const f4* wr = (const f4*)(W + (size_t)k * HH);
    float acc = 0.f;
    #pragma unroll 14
    for (int j = sub; j < H4; j += 8) {   // 14 independent iterations
        f4 w4 = wr[j];
        acc += xsum[j * 4 + 0] * w4.x;
        acc += xsum[j * 4 + 1] * w4.y;
        acc += xsum[j * 4 + 2] * w4.z;
        acc += xsum[j * 4 + 3] * w4.w;
    }
    // reduce across the octet (sub = 0..7)
    acc += __shfl_xor(acc, 1, 64);
    acc += __shfl_xor(acc, 2, 64);
    acc += __shfl_xor(acc, 4, 64);
    if (sub == 0) xpool[b * HH + k] = acc;
}

// ---------------- Kernel 2 body: one wave per segment; scores + online softmax ----------------
// NT=true: evict-first stream. NT=false: plain loads so the Infinity Cache
// retains this slice of cand across graph replays.
template <bool NT>
__device__ __forceinline__ void score_body(
        const float* __restrict__ cand,
        const float* __restrict__ xpool,
        const int* __restrict__ batch_idx,
        const int* __restrict__ label_in_seg,
        float* __restrict__ blk_loss,
        float* __restrict__ blk_acc,
        float* s_loss, float* s_acc) {
    const int wave = threadIdx.x >> 6;
    const int lane = threadIdx.x & 63;
    const int seg = blockIdx.x * 4 + wave;   // SS = 4 * gridDim.x exactly

    const int label = label_in_seg[seg];
    const long t0 = (long)seg * NC;

    float m = -INFINITY;
    float ssum = 0.f;
    float label_score = 0.f;

    for (int c = 0; c < NC; ++c) {
        const long t = t0 + c;
        const int bi = batch_idx[t];        // wave-uniform load; keeps the
                                            // candidate loop unrolled/pipelined
        const f4* cr = (const f4*)(cand + t * (long)HH);
        const f4* xr = (const f4*)(xpool + bi * HH);

        // 112 float4 covered by: lane (all 64) + 64+lane (lanes < 48)
        f4 a = NT ? __builtin_nontemporal_load(cr + lane) : cr[lane];
        f4 b = xr[lane];                    // L2-hot (57 KB total)
        float p = a.x * b.x + a.y * b.y + a.z * b.z + a.w * b.w;
        if (lane < 48) {
            f4 a2 = NT ? __builtin_nontemporal_load(cr + 64 + lane) : cr[64 + lane];
            f4 b2 = xr[64 + lane];
            p += a2.x * b2.x + a2.y * b2.y + a2.z * b2.z + a2.w * b2.w;
        }

        // 64-lane butterfly: every lane ends with the full dot
        #pragma unroll
        for (int off = 32; off > 0; off >>= 1) p += __shfl_xor(p, off, 64);

        const float score = p;
        if (c == label) label_score = score;
        const float nm = fmaxf(m, score);
        ssum = ssum * __expf(m - nm) + __expf(score - nm);
        m = nm;
    }

    if (lane == 0) {
        const float lse = m + __logf(ssum);
        s_loss[wave] = lse - label_score;
        s_acc[wave] = (label_score >= m) ? 1.f : 0.f;
    }
    __syncthreads();
    if (threadIdx.x == 0) {
        blk_loss[blockIdx.x] = (s_loss[0] + s_loss[1]) + (s_loss[2] + s_loss[3]);
        blk_acc[blockIdx.x]  = (s_acc[0] + s_acc[1]) + (s_acc[2] + s_acc[3]);
    }
}

__global__ __launch_bounds__(256) void score_kernel(
        const float* __restrict__ cand,
        const float* __restrict__ xpool,
        const int* __restrict__ batch_idx,
        const int* __restrict__ label_in_seg,
        float* __restrict__ blk_loss,
        float* __restrict__ blk_acc) {
    __shared__ float s_loss[4];
    __shared__ float s_acc[4];
    if (blockIdx.x < PIN_BLK)
        score_body<false>(cand, xpool, batch_idx, label_in_seg,
                          blk_loss, blk_acc, s_loss, s_acc);
    else
        score_body<true>(cand, xpool, batch_idx, label_in_seg,
                         blk_loss, blk_acc, s_loss, s_acc);
}

// ---------------- Kernel 3: deterministic fixed-order final reduction ----------------
__global__ __launch_bounds__(256) void reduce_kernel(const float* __restrict__ blk_loss,
                                                     const float* __restrict__ blk_acc,
                                                     float* __restrict__ out) {
    __shared__ float sl[256];
    __shared__ float sa[256];
    const int tid = threadIdx.x;
    float l = 0.f, a = 0.f;
    for (int s = tid; s < NBLK; s += 256) {
        l += blk_loss[s];
        a += blk_acc[s];
    }
    sl[tid] = l;
    sa[tid] = a;
    __syncthreads();
    for (int off = 128; off > 0; off >>= 1) {
        if (tid < off) {
            sl[tid] += sl[tid + off];
            sa[tid] += sa[tid + off];
        }
        __syncthreads();
    }
    if (tid == 0) {
        out[0] = sl[0] / (float)BB;   // loss = sum(lse - label_score) / nbatch
        out[1] = sa[0] / (float)SS;   // acc  = mean(label >= seg_max)
    }
}

extern "C" void kernel_launch(void* const* d_in, const int* in_sizes, int n_in,
                              void* d_out, int out_size, void* d_ws, size_t ws_size,
                              hipStream_t stream) {
    const float* x_mol   = (const float*)d_in[0];   // [32,40,448] f32
    const float* cand    = (const float*)d_in[1];   // [200000,448] f32
    const float* W       = (const float*)d_in[2];   // [448,448] f32
    const int*   bidx    = (const int*)d_in[3];     // [200000] i32
    const int*   label   = (const int*)d_in[4];     // [8000] i32
    float* out = (float*)d_out;                     // [loss, acc]

    // Workspace layout (floats): xpool[32*448] | blk_loss[2000] | blk_acc[2000]
    float* ws       = (float*)d_ws;
    float* xpool    = ws;                 // 14336 floats
    float* blk_loss = ws + BB * HH;       // 2000 floats
    float* blk_acc  = blk_loss + NBLK;    // 2000 floats

    dim3 pgrid(BB, 14);
    pool_kernel<<<pgrid, 256, 0, stream>>>(x_mol, W, xpool);
    score_kernel<<<NBLK, 256, 0, stream>>>(cand, xpool, bidx, label,
                                           blk_loss, blk_acc);
    reduce_kernel<<<1, 256, 0, stream>>>(blk_loss, blk_acc, out);
}